// Round 1
// baseline (764.474 us; speedup 1.0000x reference)
//
#include <hip/hip_runtime.h>

// SpMM: out = weight[idx] * segment_sum(vals[:,None] * x[cols], rows, N)
// N=50000, D=64, R=4, E=800000 (derived from in_sizes at launch).
//
// Structure: 16 lanes per edge, each lane handles a float4 feature quad.
// Gather x[col] coalesced (16B/lane), scale by w*val, atomicAdd into out[row].

#define FEAT_D 64
#define QUADS 16  // D/4

__global__ void spmm_scatter_kernel(const float* __restrict__ x,
                                    const float* __restrict__ weight,
                                    const float* __restrict__ edge_vals,
                                    const int* __restrict__ edge_rows,
                                    const int* __restrict__ edge_cols,
                                    const int* __restrict__ idx_ptr,
                                    float* __restrict__ out,
                                    int E, long long work) {
    const int idx = idx_ptr[0];
    const float w = weight[idx];
    const long long rel_off = (long long)idx * E;
    const float* __restrict__ vals = edge_vals + rel_off;
    const int* __restrict__ rows = edge_rows + rel_off;
    const int* __restrict__ cols = edge_cols + rel_off;

    long long t = (long long)blockIdx.x * blockDim.x + threadIdx.x;
    if (t >= work) return;

    const int e = (int)(t >> 4);  // edge index
    const int q = (int)(t & 15);  // feature quad (0..15)

    const int r = rows[e];
    const int c = cols[e];
    const float wv = w * vals[e];

    const float4 xv =
        *reinterpret_cast<const float4*>(x + (long long)c * FEAT_D + q * 4);

    float* op = out + (long long)r * FEAT_D + q * 4;
    atomicAdd(op + 0, wv * xv.x);
    atomicAdd(op + 1, wv * xv.y);
    atomicAdd(op + 2, wv * xv.z);
    atomicAdd(op + 3, wv * xv.w);
}

extern "C" void kernel_launch(void* const* d_in, const int* in_sizes, int n_in,
                              void* d_out, int out_size, void* d_ws, size_t ws_size,
                              hipStream_t stream) {
    const float* x         = (const float*)d_in[0];
    const float* weight    = (const float*)d_in[1];
    const float* edge_vals = (const float*)d_in[2];
    const int*   edge_rows = (const int*)d_in[3];
    const int*   edge_cols = (const int*)d_in[4];
    const int*   idx_ptr   = (const int*)d_in[5];
    float* out = (float*)d_out;

    const int R = in_sizes[1];               // weight has R elements
    const int E = in_sizes[2] / R;           // edge_vals is [R, E]

    // Output is poisoned to 0xAA before every timed launch — zero it.
    hipMemsetAsync(d_out, 0, (size_t)out_size * sizeof(float), stream);

    const long long work = (long long)E * QUADS;  // one thread per (edge, quad)
    const int block = 256;
    const long long grid = (work + block - 1) / block;

    spmm_scatter_kernel<<<dim3((unsigned)grid), dim3(block), 0, stream>>>(
        x, weight, edge_vals, edge_rows, edge_cols, idx_ptr, out, E, work);
}

// Round 2
// 339.124 us; speedup vs baseline: 2.2543x; 2.2543x over previous
//
#include <hip/hip_runtime.h>

// SpMM out = w[idx] * segment_sum(vals[:,None] * x[cols], rows, N)
// Strategy: on-device counting sort of edges by destination row (CSR), then
// one wave per row accumulates in registers -> single non-atomic 256B store.
// Replaces 51.2M f32 atomics (800MB HBM write traffic, R1 bottleneck) with
// 1.6M int atomics + 12.8MB output writes.

#define FEAT_D 64

__global__ void hist_kernel(const int* __restrict__ edge_rows,
                            const int* __restrict__ idx_ptr,
                            int* __restrict__ counts, int E) {
    int e = blockIdx.x * blockDim.x + threadIdx.x;
    if (e >= E) return;
    const int* rows = edge_rows + (long long)idx_ptr[0] * E;
    atomicAdd(&counts[rows[e]], 1);
}

// Single-block exclusive scan over counts[0..n) -> offsets[0..n].
__global__ void scan_kernel(const int* __restrict__ counts,
                            int* __restrict__ offsets, int n) {
    __shared__ int part[1024];
    const int tid = threadIdx.x;
    const int per = (n + 1023) >> 10;
    const int start = tid * per;
    const int end = min(start + per, n);
    int sum = 0;
    for (int i = start; i < end; ++i) sum += counts[i];
    part[tid] = sum;
    __syncthreads();
    // Hillis-Steele inclusive scan (read-all-then-write per step)
    for (int d = 1; d < 1024; d <<= 1) {
        int add = (tid >= d) ? part[tid - d] : 0;
        __syncthreads();
        part[tid] += add;
        __syncthreads();
    }
    int run = part[tid] - sum;  // exclusive prefix for this chunk
    for (int i = start; i < end; ++i) { offsets[i] = run; run += counts[i]; }
    if (tid == 1023) offsets[n] = part[1023];  // total
}

__global__ void scatter_kernel(const float* __restrict__ edge_vals,
                               const int* __restrict__ edge_rows,
                               const int* __restrict__ edge_cols,
                               const int* __restrict__ idx_ptr,
                               int* __restrict__ cursor,
                               int* __restrict__ scol,
                               float* __restrict__ sval, int E) {
    int e = blockIdx.x * blockDim.x + threadIdx.x;
    if (e >= E) return;
    const long long off = (long long)idx_ptr[0] * E;
    const int r = edge_rows[off + e];
    const int p = atomicAdd(&cursor[r], 1);
    scol[p] = edge_cols[off + e];
    sval[p] = edge_vals[off + e];
}

// One wave (64 lanes) per row; lane = feature index. Register accumulate.
__global__ void gather_kernel(const float* __restrict__ x,
                              const float* __restrict__ weight,
                              const int* __restrict__ idx_ptr,
                              const int* __restrict__ offsets,
                              const int* __restrict__ scol,
                              const float* __restrict__ sval,
                              float* __restrict__ out, int N) {
    const int wave = (int)((blockIdx.x * (long long)blockDim.x + threadIdx.x) >> 6);
    const int lane = threadIdx.x & 63;
    if (wave >= N) return;
    const float w = weight[idx_ptr[0]];
    const int beg = offsets[wave];
    const int end = offsets[wave + 1];
    float acc = 0.f;
    int j = beg;
    if (j < end) {
        int c = scol[j];
        float v = sval[j];
        for (++j; j < end; ++j) {
            const int cn = scol[j];      // software-pipeline next edge
            const float vn = sval[j];
            acc += v * x[(long long)c * FEAT_D + lane];
            c = cn; v = vn;
        }
        acc += v * x[(long long)c * FEAT_D + lane];
    }
    out[(long long)wave * FEAT_D + lane] = w * acc;
}

// ---- fallback (R1 atomic path) if workspace is too small ----
__global__ void spmm_scatter_kernel(const float* __restrict__ x,
                                    const float* __restrict__ weight,
                                    const float* __restrict__ edge_vals,
                                    const int* __restrict__ edge_rows,
                                    const int* __restrict__ edge_cols,
                                    const int* __restrict__ idx_ptr,
                                    float* __restrict__ out,
                                    int E, long long work) {
    const int idx = idx_ptr[0];
    const float w = weight[idx];
    const long long rel_off = (long long)idx * E;
    long long t = (long long)blockIdx.x * blockDim.x + threadIdx.x;
    if (t >= work) return;
    const int e = (int)(t >> 4);
    const int q = (int)(t & 15);
    const int r = edge_rows[rel_off + e];
    const int c = edge_cols[rel_off + e];
    const float wv = w * edge_vals[rel_off + e];
    const float4 xv = *reinterpret_cast<const float4*>(x + (long long)c * FEAT_D + q * 4);
    float* op = out + (long long)r * FEAT_D + q * 4;
    atomicAdd(op + 0, wv * xv.x);
    atomicAdd(op + 1, wv * xv.y);
    atomicAdd(op + 2, wv * xv.z);
    atomicAdd(op + 3, wv * xv.w);
}

extern "C" void kernel_launch(void* const* d_in, const int* in_sizes, int n_in,
                              void* d_out, int out_size, void* d_ws, size_t ws_size,
                              hipStream_t stream) {
    const float* x         = (const float*)d_in[0];
    const float* weight    = (const float*)d_in[1];
    const float* edge_vals = (const float*)d_in[2];
    const int*   edge_rows = (const int*)d_in[3];
    const int*   edge_cols = (const int*)d_in[4];
    const int*   idx_ptr   = (const int*)d_in[5];
    float* out = (float*)d_out;

    const int R = in_sizes[1];
    const int E = in_sizes[2] / R;
    const int N = in_sizes[0] / FEAT_D;

    // workspace layout (4B-aligned ints/floats)
    char* ws = (char*)d_ws;
    size_t o_counts  = 0;
    size_t o_offsets = o_counts  + (size_t)N * 4;
    size_t o_cursor  = o_offsets + (size_t)(N + 1) * 4;
    size_t o_scol    = o_cursor  + (size_t)N * 4;
    size_t o_sval    = o_scol    + (size_t)E * 4;
    size_t needed    = o_sval    + (size_t)E * 4;

    if (ws_size < needed) {
        // fallback: direct atomic scatter
        hipMemsetAsync(d_out, 0, (size_t)out_size * sizeof(float), stream);
        const long long work = (long long)E * 16;
        const int block = 256;
        const long long grid = (work + block - 1) / block;
        spmm_scatter_kernel<<<dim3((unsigned)grid), dim3(block), 0, stream>>>(
            x, weight, edge_vals, edge_rows, edge_cols, idx_ptr, out, E, work);
        return;
    }

    int*   counts  = (int*)(ws + o_counts);
    int*   offsets = (int*)(ws + o_offsets);
    int*   cursor  = (int*)(ws + o_cursor);
    int*   scol    = (int*)(ws + o_scol);
    float* sval    = (float*)(ws + o_sval);

    const int block = 256;
    const int egrid = (E + block - 1) / block;

    hipMemsetAsync(counts, 0, (size_t)N * 4, stream);
    hist_kernel<<<egrid, block, 0, stream>>>(edge_rows, idx_ptr, counts, E);
    scan_kernel<<<1, 1024, 0, stream>>>(counts, offsets, N);
    hipMemcpyAsync(cursor, offsets, (size_t)N * 4, hipMemcpyDeviceToDevice, stream);
    scatter_kernel<<<egrid, block, 0, stream>>>(edge_vals, edge_rows, edge_cols,
                                                idx_ptr, cursor, scol, sval, E);
    const int rows_per_block = block / 64;  // 4 waves per block
    const int ggrid = (N + rows_per_block - 1) / rows_per_block;
    gather_kernel<<<ggrid, block, 0, stream>>>(x, weight, idx_ptr, offsets,
                                               scol, sval, out, N);
}

// Round 5
// 231.843 us; speedup vs baseline: 3.2974x; 1.4627x over previous
//
#include <hip/hip_runtime.h>

// SpMM out = w[idx] * segment_sum(vals[:,None] * x[cols], rows, N)
// CSR counting-sort pipeline:
//   memset(counts) -> hist -> scanA/scanB/scanC (multi-block, writes cursor too)
//   -> scatter (packed int2 (col,val)) -> gather (wave/row, unroll-4, reg accum)

#define FEAT_D 64
#define SCAN_BLOCK 256

__global__ void hist_kernel(const int* __restrict__ edge_rows,
                            const int* __restrict__ idx_ptr,
                            int* __restrict__ counts, int E) {
    const int* rows = edge_rows + (long long)idx_ptr[0] * E;
    int t = blockIdx.x * blockDim.x + threadIdx.x;
    int e = t * 4;
    if (e + 4 <= E) {
        int4 r4 = *reinterpret_cast<const int4*>(rows + e);
        atomicAdd(&counts[r4.x], 1);
        atomicAdd(&counts[r4.y], 1);
        atomicAdd(&counts[r4.z], 1);
        atomicAdd(&counts[r4.w], 1);
    } else {
        for (; e < E; ++e) atomicAdd(&counts[rows[e]], 1);
    }
}

// Stage A: per-block inclusive scan of 256 counts -> local exclusive + block sum
__global__ void scanA_kernel(const int* __restrict__ counts,
                             int* __restrict__ local_exc,
                             int* __restrict__ block_sums, int n) {
    __shared__ int sh[SCAN_BLOCK];
    const int tid = threadIdx.x;
    const int i = blockIdx.x * SCAN_BLOCK + tid;
    const int v = (i < n) ? counts[i] : 0;
    sh[tid] = v;
    __syncthreads();
    for (int d = 1; d < SCAN_BLOCK; d <<= 1) {
        int add = (tid >= d) ? sh[tid - d] : 0;
        __syncthreads();
        sh[tid] += add;
        __syncthreads();
    }
    if (i < n) local_exc[i] = sh[tid] - v;
    if (tid == SCAN_BLOCK - 1) block_sums[blockIdx.x] = sh[tid];
}

// Stage B: single block scans block_sums (nb <= 256) -> exclusive bases; total -> offsets[n]
__global__ void scanB_kernel(int* __restrict__ block_sums,
                             int* __restrict__ offsets, int nb, int n) {
    __shared__ int sh[SCAN_BLOCK];
    const int tid = threadIdx.x;
    const int v = (tid < nb) ? block_sums[tid] : 0;
    sh[tid] = v;
    __syncthreads();
    for (int d = 1; d < SCAN_BLOCK; d <<= 1) {
        int add = (tid >= d) ? sh[tid - d] : 0;
        __syncthreads();
        sh[tid] += add;
        __syncthreads();
    }
    if (tid < nb) block_sums[tid] = sh[tid] - v;
    if (tid == SCAN_BLOCK - 1) offsets[n] = sh[tid];  // total = E
}

// Stage C: add block base; write offsets AND cursor (drops the d2d copy)
__global__ void scanC_kernel(const int* __restrict__ local_exc,
                             const int* __restrict__ block_sums,
                             int* __restrict__ offsets,
                             int* __restrict__ cursor, int n) {
    const int i = blockIdx.x * blockDim.x + threadIdx.x;
    if (i < n) {
        const int o = local_exc[i] + block_sums[blockIdx.x];
        offsets[i] = o;
        cursor[i] = o;
    }
}

__global__ void scatter_kernel(const float* __restrict__ edge_vals,
                               const int* __restrict__ edge_rows,
                               const int* __restrict__ edge_cols,
                               const int* __restrict__ idx_ptr,
                               int* __restrict__ cursor,
                               int2* __restrict__ spack, int E) {
    const long long off = (long long)idx_ptr[0] * E;
    const int* rows = edge_rows + off;
    const int* cols = edge_cols + off;
    const float* vals = edge_vals + off;
    int t = blockIdx.x * blockDim.x + threadIdx.x;
    int e = t * 2;
    if (e + 2 <= E) {
        int2 r2 = *reinterpret_cast<const int2*>(rows + e);
        int2 c2 = *reinterpret_cast<const int2*>(cols + e);
        float2 v2 = *reinterpret_cast<const float2*>(vals + e);
        int p0 = atomicAdd(&cursor[r2.x], 1);
        spack[p0] = make_int2(c2.x, __float_as_int(v2.x));
        int p1 = atomicAdd(&cursor[r2.y], 1);
        spack[p1] = make_int2(c2.y, __float_as_int(v2.y));
    } else {
        for (; e < E; ++e) {
            int p = atomicAdd(&cursor[rows[e]], 1);
            spack[p] = make_int2(cols[e], __float_as_int(vals[e]));
        }
    }
}

// One wave per row; lane = feature. Unroll-4: 4 independent x-row loads in flight.
__global__ __launch_bounds__(256, 8) void gather_kernel(
        const float* __restrict__ x,
        const float* __restrict__ weight,
        const int* __restrict__ idx_ptr,
        const int* __restrict__ offsets,
        const int2* __restrict__ spack,
        float* __restrict__ out, int N) {
    const int gtid = blockIdx.x * blockDim.x + threadIdx.x;
    const int wave = gtid >> 6;
    const int lane = threadIdx.x & 63;
    if (wave >= N) return;
    const float w = weight[idx_ptr[0]];
    const int beg = offsets[wave];
    const int end = offsets[wave + 1];
    float acc = 0.f;
    int j = beg;
    for (; j + 4 <= end; j += 4) {
        const int2 p0 = spack[j];
        const int2 p1 = spack[j + 1];
        const int2 p2 = spack[j + 2];
        const int2 p3 = spack[j + 3];
        const float x0 = x[(long long)p0.x * FEAT_D + lane];
        const float x1 = x[(long long)p1.x * FEAT_D + lane];
        const float x2 = x[(long long)p2.x * FEAT_D + lane];
        const float x3 = x[(long long)p3.x * FEAT_D + lane];
        acc += __int_as_float(p0.y) * x0 + __int_as_float(p1.y) * x1 +
               __int_as_float(p2.y) * x2 + __int_as_float(p3.y) * x3;
    }
    for (; j < end; ++j) {
        const int2 p = spack[j];
        acc += __int_as_float(p.y) * x[(long long)p.x * FEAT_D + lane];
    }
    out[(long long)wave * FEAT_D + lane] = w * acc;
}

// ---- fallback (direct atomic scatter) if workspace too small ----
__global__ void spmm_scatter_kernel(const float* __restrict__ x,
                                    const float* __restrict__ weight,
                                    const float* __restrict__ edge_vals,
                                    const int* __restrict__ edge_rows,
                                    const int* __restrict__ edge_cols,
                                    const int* __restrict__ idx_ptr,
                                    float* __restrict__ out,
                                    int E, long long work) {
    const int idx = idx_ptr[0];
    const float w = weight[idx];
    const long long rel_off = (long long)idx * E;
    long long t = (long long)blockIdx.x * blockDim.x + threadIdx.x;
    if (t >= work) return;
    const int e = (int)(t >> 4);
    const int q = (int)(t & 15);
    const int r = edge_rows[rel_off + e];
    const int c = edge_cols[rel_off + e];
    const float wv = w * edge_vals[rel_off + e];
    const float4 xv = *reinterpret_cast<const float4*>(x + (long long)c * FEAT_D + q * 4);
    float* op = out + (long long)r * FEAT_D + q * 4;
    atomicAdd(op + 0, wv * xv.x);
    atomicAdd(op + 1, wv * xv.y);
    atomicAdd(op + 2, wv * xv.z);
    atomicAdd(op + 3, wv * xv.w);
}

extern "C" void kernel_launch(void* const* d_in, const int* in_sizes, int n_in,
                              void* d_out, int out_size, void* d_ws, size_t ws_size,
                              hipStream_t stream) {
    const float* x         = (const float*)d_in[0];
    const float* weight    = (const float*)d_in[1];
    const float* edge_vals = (const float*)d_in[2];
    const int*   edge_rows = (const int*)d_in[3];
    const int*   edge_cols = (const int*)d_in[4];
    const int*   idx_ptr   = (const int*)d_in[5];
    float* out = (float*)d_out;

    const int R = in_sizes[1];
    const int E = in_sizes[2] / R;
    const int N = in_sizes[0] / FEAT_D;
    const int nb = (N + SCAN_BLOCK - 1) / SCAN_BLOCK;  // scan blocks (<=256)

    // workspace layout — spack first for 8B alignment
    char* ws = (char*)d_ws;
    size_t o_spack   = 0;
    size_t o_counts  = o_spack   + (size_t)E * 8;
    size_t o_loc     = o_counts  + (size_t)N * 4;
    size_t o_offsets = o_loc     + (size_t)N * 4;
    size_t o_cursor  = o_offsets + (size_t)(N + 1) * 4;
    size_t o_bsums   = o_cursor  + (size_t)N * 4;
    size_t needed    = o_bsums   + (size_t)nb * 4;

    if (ws_size < needed || nb > SCAN_BLOCK) {
        hipMemsetAsync(d_out, 0, (size_t)out_size * sizeof(float), stream);
        const long long work = (long long)E * 16;
        const int block = 256;
        const long long grid = (work + block - 1) / block;
        spmm_scatter_kernel<<<dim3((unsigned)grid), dim3(block), 0, stream>>>(
            x, weight, edge_vals, edge_rows, edge_cols, idx_ptr, out, E, work);
        return;
    }

    int2* spack    = (int2*)(ws + o_spack);
    int*  counts   = (int*)(ws + o_counts);
    int*  loc      = (int*)(ws + o_loc);
    int*  offsets  = (int*)(ws + o_offsets);
    int*  cursor   = (int*)(ws + o_cursor);
    int*  bsums    = (int*)(ws + o_bsums);

    const int block = 256;

    hipMemsetAsync(counts, 0, (size_t)N * 4, stream);

    const int hgrid = (E + block * 4 - 1) / (block * 4);
    hist_kernel<<<hgrid, block, 0, stream>>>(edge_rows, idx_ptr, counts, E);

    scanA_kernel<<<nb, SCAN_BLOCK, 0, stream>>>(counts, loc, bsums, N);
    scanB_kernel<<<1, SCAN_BLOCK, 0, stream>>>(bsums, offsets, nb, N);
    scanC_kernel<<<nb, SCAN_BLOCK, 0, stream>>>(loc, bsums, offsets, cursor, N);

    const int sgrid = (E + block * 2 - 1) / (block * 2);
    scatter_kernel<<<sgrid, block, 0, stream>>>(edge_vals, edge_rows, edge_cols,
                                                idx_ptr, cursor, spack, E);

    const int rows_per_block = block / 64;
    const int ggrid = (N + rows_per_block - 1) / rows_per_block;
    gather_kernel<<<ggrid, block, 0, stream>>>(x, weight, idx_ptr, offsets,
                                               spack, out, N);
}

// Round 6
// 214.910 us; speedup vs baseline: 3.5572x; 1.0788x over previous
//
#include <hip/hip_runtime.h>

// SpMM out = w[idx] * segment_sum(vals[:,None] * x[cols], rows, N)
// Per-row LINKED LIST instead of counting sort:
//   memset(head=-1) -> build (contiguous pack[e]=(col,next), atomicExch on
//   L2-resident head) -> gather (wave/row chases chain, lane=feature).
// Kills R5's 52.5MB scatter write amplification + the whole hist/scan pipeline.

#define FEAT_D 64

// pack[e] = (col, next). Written CONTIGUOUSLY (coalesced); head is 200KB,
// L2-resident, dirty lines merge.
__global__ void build_kernel(const int* __restrict__ edge_rows,
                             const int* __restrict__ edge_cols,
                             const int* __restrict__ idx_ptr,
                             int* __restrict__ head,
                             int2* __restrict__ pack, int E) {
    const long long off = (long long)idx_ptr[0] * E;
    const int* rows = edge_rows + off;
    const int* cols = edge_cols + off;
    int t = blockIdx.x * blockDim.x + threadIdx.x;
    int e = t * 2;
    if (e + 2 <= E) {
        int2 r2 = *reinterpret_cast<const int2*>(rows + e);
        int2 c2 = *reinterpret_cast<const int2*>(cols + e);
        int n0 = atomicExch(&head[r2.x], e);
        int n1 = atomicExch(&head[r2.y], e + 1);
        pack[e]     = make_int2(c2.x, n0);
        pack[e + 1] = make_int2(c2.y, n1);
    } else {
        for (; e < E; ++e) {
            int n = atomicExch(&head[rows[e]], e);
            pack[e] = make_int2(cols[e], n);
        }
    }
}

// One wave per row; lane = feature index. Chain step = one dependent 8B
// broadcast load (col,next) + independent vals[e] load + x-row load.
// Chain latency hidden by ~8192 concurrent waves.
__global__ __launch_bounds__(256, 8) void gather_kernel(
        const float* __restrict__ x,
        const float* __restrict__ weight,
        const float* __restrict__ edge_vals,
        const int* __restrict__ idx_ptr,
        const int* __restrict__ head,
        const int2* __restrict__ pack,
        float* __restrict__ out, int N, int E) {
    const int gtid = blockIdx.x * blockDim.x + threadIdx.x;
    const int row = gtid >> 6;
    const int lane = threadIdx.x & 63;
    if (row >= N) return;
    const int idx = idx_ptr[0];
    const float w = weight[idx];
    const float* __restrict__ vals = edge_vals + (long long)idx * E;

    float acc = 0.f;
    int e = head[row];
    while (e >= 0) {
        const int2 p = pack[e];        // dependent (chain) load
        const float v = vals[e];       // independent, issues in parallel
        acc += v * x[(long long)p.x * FEAT_D + lane];
        e = p.y;
    }
    out[(long long)row * FEAT_D + lane] = w * acc;
}

// ---- fallback (direct atomic scatter) if workspace too small ----
__global__ void spmm_scatter_kernel(const float* __restrict__ x,
                                    const float* __restrict__ weight,
                                    const float* __restrict__ edge_vals,
                                    const int* __restrict__ edge_rows,
                                    const int* __restrict__ edge_cols,
                                    const int* __restrict__ idx_ptr,
                                    float* __restrict__ out,
                                    int E, long long work) {
    const int idx = idx_ptr[0];
    const float w = weight[idx];
    const long long rel_off = (long long)idx * E;
    long long t = (long long)blockIdx.x * blockDim.x + threadIdx.x;
    if (t >= work) return;
    const int e = (int)(t >> 4);
    const int q = (int)(t & 15);
    const int r = edge_rows[rel_off + e];
    const int c = edge_cols[rel_off + e];
    const float wv = w * edge_vals[rel_off + e];
    const float4 xv = *reinterpret_cast<const float4*>(x + (long long)c * FEAT_D + q * 4);
    float* op = out + (long long)r * FEAT_D + q * 4;
    atomicAdd(op + 0, wv * xv.x);
    atomicAdd(op + 1, wv * xv.y);
    atomicAdd(op + 2, wv * xv.z);
    atomicAdd(op + 3, wv * xv.w);
}

extern "C" void kernel_launch(void* const* d_in, const int* in_sizes, int n_in,
                              void* d_out, int out_size, void* d_ws, size_t ws_size,
                              hipStream_t stream) {
    const float* x         = (const float*)d_in[0];
    const float* weight    = (const float*)d_in[1];
    const float* edge_vals = (const float*)d_in[2];
    const int*   edge_rows = (const int*)d_in[3];
    const int*   edge_cols = (const int*)d_in[4];
    const int*   idx_ptr   = (const int*)d_in[5];
    float* out = (float*)d_out;

    const int R = in_sizes[1];
    const int E = in_sizes[2] / R;
    const int N = in_sizes[0] / FEAT_D;

    // workspace: pack (8B aligned, E*8) then head (N*4)
    char* ws = (char*)d_ws;
    size_t o_pack = 0;
    size_t o_head = o_pack + (size_t)E * 8;
    size_t needed = o_head + (size_t)N * 4;

    if (ws_size < needed) {
        hipMemsetAsync(d_out, 0, (size_t)out_size * sizeof(float), stream);
        const long long work = (long long)E * 16;
        const int block = 256;
        const long long grid = (work + block - 1) / block;
        spmm_scatter_kernel<<<dim3((unsigned)grid), dim3(block), 0, stream>>>(
            x, weight, edge_vals, edge_rows, edge_cols, idx_ptr, out, E, work);
        return;
    }

    int2* pack = (int2*)(ws + o_pack);
    int*  head = (int*)(ws + o_head);

    const int block = 256;

    // head = -1 everywhere (0xFF bytes)
    hipMemsetAsync(head, 0xFF, (size_t)N * 4, stream);

    const int bgrid = (E + block * 2 - 1) / (block * 2);
    build_kernel<<<bgrid, block, 0, stream>>>(edge_rows, edge_cols, idx_ptr,
                                              head, pack, E);

    const int rows_per_block = block / 64;  // 4 waves per block
    const int ggrid = (N + rows_per_block - 1) / rows_per_block;
    gather_kernel<<<ggrid, block, 0, stream>>>(x, weight, edge_vals, idx_ptr,
                                               head, pack, out, N, E);
}